// Round 5
// baseline (190.588 us; speedup 1.0000x reference)
//
#include <hip/hip_runtime.h>

// Problem constants
#define SRC_N   (512 * 512)        // gaussians per batch = 262144
#define IMG_W   1024
#define IMG_HW  (1024 * 1024)
#define BATCH   4

#define K1_BLOCKS      512         // 128 chunks per batch, 2 resident/CU
#define K1_THREADS     512
#define PTS_PER_CHUNK  2048
#define CHUNKS_PER_B   128
#define NBINS          1024        // 32x32 grid of 32x32-pixel tiles
#define PREFIX_STRIDE  (NBINS + 1)
#define SENT           0xFFFFFFFFu

// ws layout (bytes)
#define PAYLOAD_BYTES  ((size_t)K1_BLOCKS * PTS_PER_CHUNK * 16)        // 16 MB
#define PREFIX_OFF     PAYLOAD_BYTES
#define PREFIX_N       (K1_BLOCKS * PREFIX_STRIDE)                     // 524800 u32
#define CORNER_OFF     (PREFIX_OFF + (((size_t)PREFIX_N * 4 + 255) & ~(size_t)255))
// corner_out: [K1_BLOCKS][12] floats, fully written each call

// ---------------------------------------------------------------------------
// K1: classify + bin. 512 blocks x 512 threads, 4 points/thread (float4).
// Private LDS histogram over 1024 bins (2 bins/thread scan), per-block
// prefix -> ws, ordered payload scatter into the block's private 32KB
// region. Corners -> 12-float LDS accumulator -> plain store. No global
// atomics anywhere.
// ---------------------------------------------------------------------------
__global__ void __launch_bounds__(512)
bin_kernel(const float* __restrict__ uv, const float* __restrict__ pos,
           float4* __restrict__ payload, unsigned* __restrict__ prefix,
           float* __restrict__ corner_out) {
    const int blk   = blockIdx.x;          // 0..511
    const int b     = blk >> 7;            // batch (uniform per block)
    const int chunk = blk & (CHUNKS_PER_B - 1);
    const int t     = threadIdx.x;

    __shared__ unsigned s_hist[NBINS];
    __shared__ unsigned s_cur[NBINS];
    __shared__ unsigned s_sum[K1_THREADS];
    __shared__ float    s_corner[12];

    s_hist[t] = 0; s_hist[t + 512] = 0;
    if (t < 12) s_corner[t] = 0.0f;
    __syncthreads();

    const float* uvb = uv  + (size_t)b * 14 * SRC_N;
    const float* pb  = pos + (size_t)b * 3  * SRC_N;
    const int n0 = chunk * PTS_PER_CHUNK + t * 4;   // 16B-aligned

    const float4 pxv = *(const float4*)&pb [n0];
    const float4 pyv = *(const float4*)&pb [SRC_N + n0];
    const float4 ux  = *(const float4*)&uvb[n0];
    const float4 uy  = *(const float4*)&uvb[SRC_N + n0];
    const float4 ov  = *(const float4*)&uvb[10 * SRC_N + n0];
    const float4 rv  = *(const float4*)&uvb[11 * SRC_N + n0];
    const float4 gv  = *(const float4*)&uvb[12 * SRC_N + n0];
    const float4 bv  = *(const float4*)&uvb[13 * SRC_N + n0];

    const float X[4]  = {pxv.x + ux.x, pxv.y + ux.y, pxv.z + ux.z, pxv.w + ux.w};
    const float Y[4]  = {pyv.x + uy.x, pyv.y + uy.y, pyv.z + uy.z, pyv.w + uy.w};
    const float O[4]  = {ov.x, ov.y, ov.z, ov.w};
    const float CR[4] = {rv.x, rv.y, rv.z, rv.w};
    const float CG[4] = {gv.x, gv.y, gv.z, gv.w};
    const float CB[4] = {bv.x, bv.y, bv.z, bv.w};

    unsigned packed[4];
    float R[4], G[4], B[4];

#pragma unroll
    for (int j = 0; j < 4; ++j) {
        // truncating cast (matches .astype(int32)), then clamp
        int px = (int)((X[j] + 1.0f) * 512.0f);
        int py = (int)((Y[j] + 1.0f) * 512.0f);
        px = min(max(px, 0), IMG_W - 1);
        py = min(max(py, 0), IMG_W - 1);

        const float opac = 1.0f / (1.0f + __expf(-O[j]));
        R[j] = CR[j] * opac; G[j] = CG[j] * opac; B[j] = CB[j] * opac;

        const bool xe = (px == 0) | (px == IMG_W - 1);
        const bool ye = (py == 0) | (py == IMG_W - 1);
        if (xe & ye) {
            const int ci = ((py != 0) ? 2 : 0) + ((px != 0) ? 1 : 0);
            atomicAdd(&s_corner[ci * 3 + 0], R[j]);
            atomicAdd(&s_corner[ci * 3 + 1], G[j]);
            atomicAdd(&s_corner[ci * 3 + 2], B[j]);
            packed[j] = SENT;
        } else {
            const int bin = ((py >> 5) << 5) | (px >> 5);     // 0..1023
            atomicAdd(&s_hist[bin], 1u);
            packed[j] = ((unsigned)bin << 10) | ((unsigned)(py & 31) << 5)
                      | (unsigned)(px & 31);
        }
    }
    __syncthreads();

    // pair-scan: thread t owns bins 2t, 2t+1
    const unsigned h0 = s_hist[2 * t], h1 = s_hist[2 * t + 1];
    s_sum[t] = h0 + h1;
    __syncthreads();
    for (int d = 1; d < K1_THREADS; d <<= 1) {
        const unsigned v = (t >= d) ? s_sum[t - d] : 0u;
        __syncthreads();
        s_sum[t] += v;
        __syncthreads();
    }
    const unsigned incl = s_sum[t];
    const unsigned e0 = incl - h0 - h1;      // exclusive prefix of bin 2t
    s_cur[2 * t]     = e0;
    s_cur[2 * t + 1] = e0 + h0;
    unsigned* pf = prefix + (size_t)blk * PREFIX_STRIDE;
    pf[2 * t]     = e0;
    pf[2 * t + 1] = e0 + h0;
    if (t == K1_THREADS - 1) pf[NBINS] = incl;
    if (t < 12) corner_out[blk * 12 + t] = s_corner[t];
    __syncthreads();

    // ordered payload scatter into private region
    float4* pbase = payload + (size_t)blk * PTS_PER_CHUNK;
#pragma unroll
    for (int j = 0; j < 4; ++j) {
        if (packed[j] != SENT) {
            const int bin = packed[j] >> 10;
            const unsigned p = atomicAdd(&s_cur[bin], 1u);
            pbase[p] = make_float4(__uint_as_float(packed[j] & 0x3FFu),
                                   R[j], G[j], B[j]);
        }
    }
}

// ---------------------------------------------------------------------------
// K2: one 256-thread block per (batch, 32x32 tile). 12KB LDS sub-image ->
// 8 resident blocks/CU. Gather runs from 128 source chunks (2 threads each),
// LDS-atomic accumulate, fold corner partials (parallel over 128 threads),
// dense clipped float4 stores.
// ---------------------------------------------------------------------------
__global__ void __launch_bounds__(256)
accum_kernel(const float4* __restrict__ payload, const unsigned* __restrict__ prefix,
             const float* __restrict__ corner_out, float* __restrict__ out) {
    const int bg   = blockIdx.x;           // 0..4095
    const int b    = bg >> 10;
    const int tile = bg & (NBINS - 1);
    const int ty   = tile >> 5, tx = tile & 31;
    const int t    = threadIdx.x;

    __shared__ float    acc[3 * 1024];     // 12 KB: [c][ly*32+lx]
    __shared__ unsigned rs[CHUNKS_PER_B], re[CHUNKS_PER_B];

    float4* acc4 = (float4*)acc;
    const float4 z4 = make_float4(0.f, 0.f, 0.f, 0.f);
    acc4[t] = z4; acc4[256 + t] = z4; acc4[512 + t] = z4;
    if (t < 128) rs[t]       = prefix[(size_t)(b * 128 + t)        * PREFIX_STRIDE + tile];
    else         re[t - 128] = prefix[(size_t)(b * 128 + (t - 128)) * PREFIX_STRIDE + tile + 1];
    __syncthreads();

    // 2 threads cooperate per source chunk
    const int chunk = t & 127;
    const int sub   = t >> 7;
    const unsigned s = rs[chunk], e = re[chunk];
    const float4* pbase = payload + (size_t)(b * 128 + chunk) * PTS_PER_CHUNK;
    for (unsigned i = s + sub; i < e; i += 2) {
        const float4 v = pbase[i];
        const unsigned idx = __float_as_uint(v.x) & 0x3FFu;
        atomicAdd(&acc[idx],        v.y);
        atomicAdd(&acc[1024 + idx], v.z);
        atomicAdd(&acc[2048 + idx], v.w);
    }

    // corner fold (only the 4 corner tiles per batch), parallel over chunks
    const bool cx = (tx == 0) | (tx == 31);
    const bool cy = (ty == 0) | (ty == 31);
    if (cx & cy & (t < 128)) {
        const int ci   = ((ty == 31) ? 2 : 0) + ((tx == 31) ? 1 : 0);
        const int cpix = ((ty == 31) ? 992 : 0) + ((tx == 31) ? 31 : 0);
        const float* cp = corner_out + (size_t)(b * 128 + t) * 12 + ci * 3;
        atomicAdd(&acc[cpix],        cp[0]);
        atomicAdd(&acc[1024 + cpix], cp[1]);
        atomicAdd(&acc[2048 + cpix], cp[2]);
    }
    __syncthreads();

    // dense clipped store: thread t -> 4 consecutive pixels, 3 channels
    float* ob = out + (size_t)b * 3 * IMG_HW;
    const int ly  = t >> 3;
    const int lx4 = (t & 7) << 2;
    const int gy  = ty * 32 + ly;
    const int gx  = tx * 32 + lx4;
#pragma unroll
    for (int c = 0; c < 3; ++c) {
        float4 v = acc4[c * 256 + t];
        v.x = fminf(fmaxf(v.x, 0.f), 1.f);
        v.y = fminf(fmaxf(v.y, 0.f), 1.f);
        v.z = fminf(fmaxf(v.z, 0.f), 1.f);
        v.w = fminf(fmaxf(v.w, 0.f), 1.f);
        *(float4*)(ob + (size_t)c * IMG_HW + (size_t)gy * IMG_W + gx) = v;
    }
}

extern "C" void kernel_launch(void* const* d_in, const int* in_sizes, int n_in,
                              void* d_out, int out_size, void* d_ws, size_t ws_size,
                              hipStream_t stream) {
    const float* uv  = (const float*)d_in[0];   // (4,14,512,512)
    const float* pos = (const float*)d_in[1];   // (4,3,512,512)
    float* out = (float*)d_out;                 // (4,3,1024,1024)

    float4*   payload    = (float4*)d_ws;                          // 16 MB
    unsigned* prefix     = (unsigned*)((char*)d_ws + PREFIX_OFF);  // 2.1 MB
    float*    corner_out = (float*)((char*)d_ws + CORNER_OFF);     // 24 KB

    // No memsets: prefix/corner fully rewritten each call; payload only read
    // within [prefix[bin], prefix[bin+1]) ranges written this call.
    bin_kernel<<<K1_BLOCKS, K1_THREADS, 0, stream>>>(uv, pos, payload, prefix, corner_out);
    accum_kernel<<<BATCH * NBINS, 256, 0, stream>>>(payload, prefix, corner_out, out);
}